// Round 2
// baseline (603.419 us; speedup 1.0000x reference)
//
#include <hip/hip_runtime.h>

#define T_HORIZON 50
#define NU 4
#define NY 4
#define KH 32
#define NW (8*KH + KH + KH + 1)   // Wh(256) + bh(32) + Wo(32) + bo(1) = 321

__device__ __forceinline__ float fast_tanh(float v) {
    // tanh(v) = 1 - 2/(exp(2v)+1), exp via exp2: 2v*log2(e) = v*2.885390081777927
    float e = __builtin_amdgcn_exp2f(v * 2.88539008177792681472f);
    float r = __builtin_amdgcn_rcpf(e + 1.0f);
    return fmaf(-2.0f, r, 1.0f);
}

__global__ __launch_bounds__(256, 1) void rollout_kernel(
    const float* __restrict__ u,    // (B, 50, 4)
    const float* __restrict__ y0g,  // (B, 4)
    const float* __restrict__ Whg,  // (8, 32)
    const float* __restrict__ bhg,  // (32)
    const float* __restrict__ Wog,  // (32, 1)
    const float* __restrict__ bog,  // (1)
    float* __restrict__ out)        // (B, 50, 1)
{
    __shared__ float sW[NW];
    const int tid = threadIdx.x;

    // Stage all 321 weights into LDS. Block has 256 threads, so the tail
    // (bh[32] | Wo[32] | bo[1], indices 256..320) is staged by tid 0..64.
    if (tid < 8*KH) sW[tid] = Whg[tid];
    if (tid < 65) {
        float v;
        if (tid < KH)          v = bhg[tid];
        else if (tid < 2*KH)   v = Wog[tid - KH];
        else                   v = bog[0];
        sW[8*KH + tid] = v;
    }
    __syncthreads();

    // Per-thread register copies of all weights (constant indices after full
    // unroll -> SROA promotes arrays to VGPRs).
    float wh[8][KH];
    float bhr[KH], wor[KH];
#pragma unroll
    for (int i = 0; i < 8; ++i)
#pragma unroll
        for (int j = 0; j < KH; ++j)
            wh[i][j] = sW[i*KH + j];
#pragma unroll
    for (int j = 0; j < KH; ++j) {
        bhr[j] = sW[8*KH + j];
        wor[j] = sW[9*KH + j];
    }
    const float bor = sW[10*KH];

    const int b = blockIdx.x * 256 + tid;
    const float4* ub = (const float4*)(u + (size_t)b * T_HORIZON * NU);
    float* ob = out + (size_t)b * T_HORIZON;

    float4 yv = *(const float4*)(y0g + (size_t)b * NY);
    float y1 = yv.x, y2 = yv.y, y3 = yv.z, y4 = yv.w;

    float4 un = ub[0];   // prefetched u_t
    for (int t = 0; t < T_HORIZON; ++t) {
        float4 uc = un;
        if (t + 1 < T_HORIZON) un = ub[t + 1];

        // pred accumulation tree (4 partials) to break the serial FMA chain
        float pA = 0.0f, pB = 0.0f, pC = 0.0f, pD = 0.0f;
#pragma unroll
        for (int j = 0; j < KH; ++j) {
            float a = fmaf(uc.x, wh[0][j], bhr[j]);
            a = fmaf(uc.y, wh[1][j], a);
            a = fmaf(uc.z, wh[2][j], a);
            a = fmaf(uc.w, wh[3][j], a);
            a = fmaf(y1,   wh[4][j], a);
            a = fmaf(y2,   wh[5][j], a);
            a = fmaf(y3,   wh[6][j], a);
            a = fmaf(y4,   wh[7][j], a);
            float m = fast_tanh(a) * wor[j];
            if ((j & 3) == 0)      pA += m;
            else if ((j & 3) == 1) pB += m;
            else if ((j & 3) == 2) pC += m;
            else                   pD += m;
        }
        float pred = bor + ((pA + pB) + (pC + pD));

        ob[t] = pred;

        // y_new = [pred, y_old[0:3]]
        y4 = y3; y3 = y2; y2 = y1; y1 = pred;
    }
}

extern "C" void kernel_launch(void* const* d_in, const int* in_sizes, int n_in,
                              void* d_out, int out_size, void* d_ws, size_t ws_size,
                              hipStream_t stream) {
    const float* u   = (const float*)d_in[0];
    const float* y0g = (const float*)d_in[1];
    const float* Whg = (const float*)d_in[2];
    const float* bhg = (const float*)d_in[3];
    const float* Wog = (const float*)d_in[4];
    const float* bog = (const float*)d_in[5];
    float* out = (float*)d_out;

    const int B = in_sizes[1] / NY;          // 524288
    dim3 grid(B / 256), block(256);
    rollout_kernel<<<grid, block, 0, stream>>>(u, y0g, Whg, bhg, Wog, bog, out);
}

// Round 4
// 326.631 us; speedup vs baseline: 1.8474x; 1.8474x over previous
//
#include <hip/hip_runtime.h>

#define T_HORIZON 50
#define NU 4
#define NY 4
#define KH 32
#define NW (8*KH + KH + KH + 1)   // Wh(256) + bh(32) + Wo(32) + bo(1) = 321
#define BPB 64                    // batch elements per block (4 waves x 16)

typedef float v2f __attribute__((ext_vector_type(2)));

__device__ __forceinline__ v2f fma2(v2f a, v2f b, v2f c) {
    return __builtin_elementwise_fma(a, b, c);   // v_pk_fma_f32: IEEE fma per component
}

__device__ __forceinline__ float fast_tanh(float v) {
    // tanh(v) = 1 - 2/(exp(2v)+1); identical to the round-2 passing kernel.
    float e = __builtin_amdgcn_exp2f(v * 2.88539008177792681472f);
    float r = __builtin_amdgcn_rcpf(e + 1.0f);
    return fmaf(-2.0f, r, 1.0f);
}

__global__ __launch_bounds__(256, 3) void rollout_kernel(
    const float* __restrict__ u,    // (B, 50, 4)
    const float* __restrict__ y0g,  // (B, 4)
    const float* __restrict__ Whg,  // (8, 32)
    const float* __restrict__ bhg,  // (32)
    const float* __restrict__ Wog,  // (32, 1)
    const float* __restrict__ bog,  // (1)
    float* __restrict__ out)        // (B, 50, 1)
{
    __shared__ float sW[NW];
    __shared__ __align__(16) float sOut[BPB * T_HORIZON];  // [b_local][t]
    const int tid = threadIdx.x;

    // Stage all 321 weights into LDS (tail 256..320 staged by tid 0..64).
    if (tid < 8*KH) sW[tid] = Whg[tid];
    if (tid < 65) {
        float v;
        if (tid < KH)        v = bhg[tid];
        else if (tid < 2*KH) v = Wog[tid - KH];
        else                 v = bog[0];
        sW[8*KH + tid] = v;
    }
    __syncthreads();

    const int lane = tid & 63;
    const int widx = tid >> 6;       // wave in block, 0..3
    const int bsub = lane & 15;      // batch element within wave
    const int jg   = lane >> 4;      // mod-4 class: lane owns j = jg + 4k, k=0..7
    const int bl   = widx * 16 + bsub;
    const int b    = blockIdx.x * BPB + bl;

    // Per-lane register weights for its 8 owned j's (k ascending = j ascending
    // within the class, matching round-2's pA..pD accumulation order).
    // v2f pair p holds components k=2p (j=jg+8p) and k=2p+1 (j=jg+8p+4).
    v2f wh2[8][4];
#pragma unroll
    for (int i = 0; i < 8; ++i)
#pragma unroll
        for (int p = 0; p < 4; ++p)
            wh2[i][p] = v2f{sW[i*KH + jg + 8*p], sW[i*KH + jg + 8*p + 4]};
    v2f bh2[4];
    float work[8];
#pragma unroll
    for (int p = 0; p < 4; ++p)
        bh2[p] = v2f{sW[8*KH + jg + 8*p], sW[8*KH + jg + 8*p + 4]};
#pragma unroll
    for (int k = 0; k < 8; ++k)
        work[k] = sW[9*KH + jg + 4*k];
    const float bor = sW[10*KH];

    const float4* ub = (const float4*)(u + (size_t)b * T_HORIZON * NU);
    float4 yv = *(const float4*)(y0g + (size_t)b * NY);
    float y1 = yv.x, y2 = yv.y, y3 = yv.z, y4 = yv.w;

    float4 un = ub[0];
    for (int t = 0; t < T_HORIZON; ++t) {
        float4 uc = un;
        if (t + 1 < T_HORIZON) un = ub[t + 1];

        // pre-activation chain, identical order to round 2: bh, u0..u3, y1..y4
        float aa[8];
#pragma unroll
        for (int p = 0; p < 4; ++p) {
            v2f a = fma2(v2f{uc.x, uc.x}, wh2[0][p], bh2[p]);
            a = fma2(v2f{uc.y, uc.y}, wh2[1][p], a);
            a = fma2(v2f{uc.z, uc.z}, wh2[2][p], a);
            a = fma2(v2f{uc.w, uc.w}, wh2[3][p], a);
            a = fma2(v2f{y1, y1},     wh2[4][p], a);
            a = fma2(v2f{y2, y2},     wh2[5][p], a);
            a = fma2(v2f{y3, y3},     wh2[6][p], a);
            a = fma2(v2f{y4, y4},     wh2[7][p], a);
            aa[2*p]     = a.x;
            aa[2*p + 1] = a.y;
        }

        // serial class accumulation, verbatim round-2 statement forms
        float pcls = 0.0f;
#pragma unroll
        for (int k = 0; k < 8; ++k) {
            float m = fast_tanh(aa[k]) * work[k];
            pcls += m;
        }

        // (pA+pB)+(pC+pD) exactly (IEEE add commutative -> all lanes bitwise equal)
        float partial = pcls;
        partial += __shfl_xor(partial, 16, 64);
        partial += __shfl_xor(partial, 32, 64);
        float pred = bor + partial;

        if (jg == 0) sOut[bl * T_HORIZON + t] = pred;

        y4 = y3; y3 = y2; y2 = y1; y1 = pred;
    }
    __syncthreads();

    // Coalesced flush: block's out region is contiguous 64*50 floats.
    const float4* s4 = (const float4*)sOut;
    float4* o4 = (float4*)(out + (size_t)blockIdx.x * BPB * T_HORIZON);
#pragma unroll
    for (int k = 0; k < 4; ++k) {
        int idx = k * 256 + tid;
        if (idx < (BPB * T_HORIZON) / 4) o4[idx] = s4[idx];
    }
}

extern "C" void kernel_launch(void* const* d_in, const int* in_sizes, int n_in,
                              void* d_out, int out_size, void* d_ws, size_t ws_size,
                              hipStream_t stream) {
    const float* u   = (const float*)d_in[0];
    const float* y0g = (const float*)d_in[1];
    const float* Whg = (const float*)d_in[2];
    const float* bhg = (const float*)d_in[3];
    const float* Wog = (const float*)d_in[4];
    const float* bog = (const float*)d_in[5];
    float* out = (float*)d_out;

    const int B = in_sizes[1] / NY;          // 524288
    dim3 grid(B / BPB), block(256);
    rollout_kernel<<<grid, block, 0, stream>>>(u, y0g, Whg, bhg, Wog, bog, out);
}